// Round 8
// baseline (424.556 us; speedup 1.0000x reference)
//
#include <hip/hip_runtime.h>
#include <hip/hip_bf16.h>

#define N_ATOMS 100000
#define K_NBR   64
#define N_STRUCT 32
#define HID     128
#define N_EDGE  (N_ATOMS * K_NBR)       // 6,400,000
#define ATOMS_PB 32                     // atoms per edge block
#define EDGES_PB (ATOMS_PB * K_NBR)     // 2048
#define NBLK_EL (N_ATOMS / ATOMS_PB)    // 3125 (exact)
#define NBLK_A  ((N_ATOMS + 63) / 64)   // 1563

typedef unsigned int uint;

#if __has_builtin(__builtin_amdgcn_exp2f)
#define EXP2(v) __builtin_amdgcn_exp2f(v)
#else
#define EXP2(v) __expf((v) * 0.69314718056f)
#endif

__device__ __forceinline__ uint bf_rne(float f) {        // fp32 -> bf16 bits (RNE)
    uint u = __float_as_uint(f);
    return (u + 0x7fffu + ((u >> 16) & 1u)) >> 16;
}
__device__ __forceinline__ float ubf_lo(uint u) { return __uint_as_float(u << 16); }
__device__ __forceinline__ float ubf_hi(uint u) { return __uint_as_float(u & 0xffff0000u); }

// ---------------------------------------------------------------------------
// Weight prep (1 block):
//   pw4[d] = {2log2e*W1[0,d], 2log2e*W1[1,d], 2log2e*W1[2,d], w2[d]}
//   gw4[d] = {4*w2*W1[0,d],   4*w2*W1[1,d],   4*w2*W1[2,d],   0}
// identities: ex = e^{2p} = exp2(x·pw); r = 1/(1+ex); t = 1-2r;
//             e = sumw2 - 2 sum w2 r; (1-t^2)/4 = r - r^2.
// ---------------------------------------------------------------------------
__global__ void prep_kernel(const float* __restrict__ W1, const float* __restrict__ w2,
                            float4* __restrict__ pw4, float4* __restrict__ gw4,
                            float* __restrict__ sumw2)
{
    const float L2E2 = 2.885390082f;     // 2*log2(e)
    int d = threadIdx.x;                 // 128 threads
    float w0 = W1[d], w1 = W1[HID + d], wc = W1[2 * HID + d], wv = w2[d];
    pw4[d] = make_float4(L2E2 * w0, L2E2 * w1, L2E2 * wc, wv);
    gw4[d] = make_float4(4.f * wv * w0, 4.f * wv * w1, 4.f * wv * wc, 0.f);
    float v = wv;
    for (int off = 32; off; off >>= 1) v += __shfl_down(v, off, 64);
    __shared__ float sw_[2];
    if ((threadIdx.x & 63) == 0) sw_[threadIdx.x >> 6] = v;
    __syncthreads();
    if (threadIdx.x == 0) sumw2[0] = sw_[0] + sw_[1];
}

// ---------------------------------------------------------------------------
// Edge MLP with block-local compaction (R6 structure): block owns 32 atoms
// (2048 edges). Phase A compacts unmasked local ids into LDS + zeroes masked
// gr8 slots. Phase B runs the dense exp-tanh d-loop over the ~1024 list.
// ---------------------------------------------------------------------------
__global__ __launch_bounds__(256) void edge_local(
    const float* __restrict__ x, const int* __restrict__ mask,
    const int* __restrict__ batch,
    const float4* __restrict__ pw4, const float4* __restrict__ gw4,
    const float* __restrict__ sumw2p,
    uint2* __restrict__ gr8, float* __restrict__ part)
{
    __shared__ unsigned short list[EDGES_PB];
    __shared__ int   lcnt;
    __shared__ float sp[N_STRUCT];
    __shared__ int   sbatch[ATOMS_PB];

    const int tid = threadIdx.x, lane = tid & 63;
    const int ebase = blockIdx.x * EDGES_PB;

    if (tid == 0) lcnt = 0;
    if (tid < N_STRUCT) sp[tid] = 0.f;
    if (tid < ATOMS_PB) sbatch[tid] = batch[blockIdx.x * ATOMS_PB + tid];
    __syncthreads();

    #pragma unroll
    for (int p = 0; p < EDGES_PB / 256; ++p) {           // 8 passes, coalesced
        int le = p * 256 + tid;
        int m = mask[ebase + le];
        unsigned long long bal = __ballot(m == 0);
        int wcnt = __popcll(bal);
        int pre  = __popcll(bal & ((1ull << lane) - 1ull));
        int wbase;
        if (lane == 0) wbase = atomicAdd(&lcnt, wcnt);   // block-local ticket
        wbase = __shfl(wbase, 0, 64);
        if (m == 0) list[wbase + pre] = (unsigned short)le;
        else        gr8[ebase + le] = make_uint2(0u, 0u);
    }
    __syncthreads();

    const int L = lcnt;
    const float sumw2 = sumw2p[0];

    for (int i = tid; i < L; i += 256) {
        int le  = list[i];
        int eid = ebase + le;
        const float* xp = x + (size_t)eid * 3;
        float x0 = xp[0], x1 = xp[1], x2 = xp[2];
        float rsum = 0.f, g0 = 0.f, g1 = 0.f, g2 = 0.f;
        for (int d = 0; d < HID; d += 4) {
            float4 wa = pw4[d], wb = pw4[d + 1], wc = pw4[d + 2], wd = pw4[d + 3];
            float4 Ga = gw4[d], Gb = gw4[d + 1], Gc = gw4[d + 2], Gd = gw4[d + 3];
            float ea = EXP2(fmaf(x0, wa.x, fmaf(x1, wa.y, x2 * wa.z)));
            float eb = EXP2(fmaf(x0, wb.x, fmaf(x1, wb.y, x2 * wb.z)));
            float ec = EXP2(fmaf(x0, wc.x, fmaf(x1, wc.y, x2 * wc.z)));
            float ed = EXP2(fmaf(x0, wd.x, fmaf(x1, wd.y, x2 * wd.z)));
            float aa = ea + 1.f, ab = eb + 1.f, ac = ec + 1.f, ad = ed + 1.f;
            float pab = aa * ab, pcd = ac * ad;
            float q   = __builtin_amdgcn_rcpf(pab * pcd);     // one rcp per 4 d
            float qab = q * pcd, qcd = q * pab;
            float ra = qab * ab, rb = qab * aa, rc = qcd * ad, rd = qcd * ac;
            rsum = fmaf(wa.w, ra, rsum);
            rsum = fmaf(wb.w, rb, rsum);
            rsum = fmaf(wc.w, rc, rsum);
            rsum = fmaf(wd.w, rd, rsum);
            float sa = fmaf(-ra, ra, ra);                     // r-r^2 = (1-t^2)/4
            float sb = fmaf(-rb, rb, rb);
            float sc = fmaf(-rc, rc, rc);
            float sd = fmaf(-rd, rd, rd);
            g0 = fmaf(sa, Ga.x, g0); g1 = fmaf(sa, Ga.y, g1); g2 = fmaf(sa, Ga.z, g2);
            g0 = fmaf(sb, Gb.x, g0); g1 = fmaf(sb, Gb.y, g1); g2 = fmaf(sb, Gb.z, g2);
            g0 = fmaf(sc, Gc.x, g0); g1 = fmaf(sc, Gc.y, g1); g2 = fmaf(sc, Gc.z, g2);
            g0 = fmaf(sd, Gd.x, g0); g1 = fmaf(sd, Gd.y, g1); g2 = fmaf(sd, Gd.z, g2);
        }
        float e = fmaf(-2.f, rsum, sumw2);
        uint lo = bf_rne(g0) | (bf_rne(g1) << 16);
        uint hi = bf_rne(g2);
        gr8[eid] = make_uint2(lo, hi);
        atomicAdd(&sp[sbatch[le >> 6]], e);
    }
    __syncthreads();
    if (tid < N_STRUCT) part[(size_t)tid * NBLK_EL + blockIdx.x] = sp[tid];
}

// ---------------------------------------------------------------------------
// Gather-pipelined forces: block = 64 atoms, wave = 16 atoms. Three-phase:
// (1) compute all 16 gather indices (LDS nidx tile + coalesced pos/mask);
// (2) issue all 16 random gathers + 16 coalesced own-reads (32 loads in
//     flight per wave — latency hiding via Little's law);
// (3) shuffle-reduce + store. Blocks 0..31 also reduce preds partials.
// ---------------------------------------------------------------------------
__global__ __launch_bounds__(256) void atom_fused(
    const uint2* __restrict__ gr8, const int* __restrict__ nidx,
    const int* __restrict__ pos, const int* __restrict__ mask,
    const float* __restrict__ part, float* __restrict__ out)
{
    __shared__ int tile[64][65];
    __shared__ float sv[4];
    const int tid = threadIdx.x, lane = tid & 63, w = tid >> 6;
    const int n0 = blockIdx.x * 64;

    #pragma unroll
    for (int i = 0; i < 16; ++i) {                 // coalesced read of nidx[K,N]
        int k = i * 4 + w, n = n0 + lane;
        tile[k][lane] = (n < N_ATOMS) ? nidx[k * N_ATOMS + n] : 0;
    }
    __syncthreads();

    const int nw = n0 + w * 16;                    // wave's first atom

    int g[16];
    #pragma unroll
    for (int j = 0; j < 16; ++j) {                 // phase 1: indices
        int n = nw + j;
        bool v = (n < N_ATOMS);
        int ei = n * 64 + lane;
        int m  = v ? mask[ei] : 1;
        int ps = (v && m == 0) ? pos[ei] : 0;
        g[j] = (v && m == 0) ? (tile[lane][w * 16 + j] * 64 + ps) : -1;
    }

    uint2 bg[16], own[16];
    #pragma unroll
    for (int j = 0; j < 16; ++j) {                 // phase 2a: random gathers
        bg[j] = make_uint2(0u, 0u);
        if (g[j] >= 0) bg[j] = gr8[g[j]];          // aligned 8B, exec-masked
    }
    #pragma unroll
    for (int j = 0; j < 16; ++j) {                 // phase 2b: own (coalesced)
        int n = nw + j;
        own[j] = (n < N_ATOMS) ? gr8[n * 64 + lane] : make_uint2(0u, 0u);
    }

    #pragma unroll
    for (int j = 0; j < 16; ++j) {                 // phase 3: reduce + store
        float f0 = ubf_lo(own[j].x) - ubf_lo(bg[j].x);
        float f1 = ubf_hi(own[j].x) - ubf_hi(bg[j].x);
        float f2 = ubf_lo(own[j].y) - ubf_lo(bg[j].y);
        for (int off = 32; off; off >>= 1) {
            f0 += __shfl_down(f0, off, 64);
            f1 += __shfl_down(f1, off, 64);
            f2 += __shfl_down(f2, off, 64);
        }
        int n = nw + j;
        if (lane == 0 && n < N_ATOMS) {
            float* fo = out + N_STRUCT + (size_t)n * 3;
            fo[0] = f0; fo[1] = f1; fo[2] = f2;
        }
    }

    if (blockIdx.x < N_STRUCT) {                   // fused preds reduction
        int s = blockIdx.x;
        float v = 0.f;
        for (int i = tid; i < NBLK_EL; i += 256) v += part[(size_t)s * NBLK_EL + i];
        for (int off = 32; off; off >>= 1) v += __shfl_down(v, off, 64);
        if (lane == 0) sv[w] = v;
        __syncthreads();
        if (tid == 0) out[s] = sv[0] + sv[1] + sv[2] + sv[3];
    }
}

// ---------------------------------------------------------------------------
extern "C" void kernel_launch(void* const* d_in, const int* in_sizes, int n_in,
                              void* d_out, int out_size, void* d_ws, size_t ws_size,
                              hipStream_t stream)
{
    const float* x    = (const float*)d_in[0];
    const int*   nidx = (const int*)d_in[1];   // [K, N]
    const int*   npos = (const int*)d_in[2];   // [N, K]
    const int*   mask = (const int*)d_in[3];   // [N, K]
    const int*   bidx = (const int*)d_in[4];   // [N]
    const float* W1   = (const float*)d_in[5]; // [3, HID]
    const float* w2   = (const float*)d_in[6]; // [HID]
    float* out = (float*)d_out;

    char* ws = (char*)d_ws;
    uint2* gr8  = (uint2*)ws;                                       // 51.2 MB
    float* part = (float*)(ws + (size_t)N_EDGE * 8);                // 400 KB
    char*  tail = ws + (size_t)N_EDGE * 8
                     + (size_t)N_STRUCT * NBLK_EL * sizeof(float);
    float4* pw4   = (float4*)tail;                                  // 2 KB
    float4* gw4   = (float4*)(tail + HID * 16);                     // 2 KB
    float*  sumw2 = (float*)(tail + 2 * HID * 16);

    hipLaunchKernelGGL(prep_kernel, dim3(1), dim3(128), 0, stream,
                       W1, w2, pw4, gw4, sumw2);
    hipLaunchKernelGGL(edge_local, dim3(NBLK_EL), dim3(256), 0, stream,
                       x, mask, bidx, pw4, gw4, sumw2, gr8, part);
    hipLaunchKernelGGL(atom_fused, dim3(NBLK_A), dim3(256), 0, stream,
                       gr8, nidx, npos, mask, part, out);
}

// Round 9
// 369.082 us; speedup vs baseline: 1.1503x; 1.1503x over previous
//
#include <hip/hip_runtime.h>
#include <hip/hip_bf16.h>

#define N_ATOMS 100000
#define K_NBR   64
#define N_STRUCT 32
#define HID     128
#define N_EDGE  (N_ATOMS * K_NBR)       // 6,400,000
#define ATOMS_PB 32                     // atoms per edge block
#define EDGES_PB (ATOMS_PB * K_NBR)     // 2048
#define NBLK_EL (N_ATOMS / ATOMS_PB)    // 3125 (exact)
#define NBLK_A  ((N_ATOMS + 63) / 64)   // 1563

typedef unsigned int uint;
typedef unsigned long long ull;

#if __has_builtin(__builtin_amdgcn_exp2f)
#define EXP2(v) __builtin_amdgcn_exp2f(v)
#else
#define EXP2(v) __expf((v) * 0.69314718056f)
#endif

__device__ __forceinline__ uint bf_rne(float f) {        // fp32 -> bf16 bits (RNE)
    uint u = __float_as_uint(f);
    return (u + 0x7fffu + ((u >> 16) & 1u)) >> 16;
}
__device__ __forceinline__ float ubf_lo(uint u) { return __uint_as_float(u << 16); }
__device__ __forceinline__ float ubf_hi(uint u) { return __uint_as_float(u & 0xffff0000u); }

// ---------------------------------------------------------------------------
// Weight prep (1 block):
//   pw4[d] = {2log2e*W1[0,d], 2log2e*W1[1,d], 2log2e*W1[2,d], w2[d]}
//   gw4[d] = {4*w2*W1[0,d],   4*w2*W1[1,d],   4*w2*W1[2,d],   0}
// identities: ex = e^{2p} = exp2(x·pw); r = 1/(1+ex); t = 1-2r;
//             e = sumw2 - 2 sum w2 r; (1-t^2)/4 = r - r^2.
// ---------------------------------------------------------------------------
__global__ void prep_kernel(const float* __restrict__ W1, const float* __restrict__ w2,
                            float4* __restrict__ pw4, float4* __restrict__ gw4,
                            float* __restrict__ sumw2)
{
    const float L2E2 = 2.885390082f;     // 2*log2(e)
    int d = threadIdx.x;                 // 128 threads
    float w0 = W1[d], w1 = W1[HID + d], wc = W1[2 * HID + d], wv = w2[d];
    pw4[d] = make_float4(L2E2 * w0, L2E2 * w1, L2E2 * wc, wv);
    gw4[d] = make_float4(4.f * wv * w0, 4.f * wv * w1, 4.f * wv * wc, 0.f);
    float v = wv;
    for (int off = 32; off; off >>= 1) v += __shfl_down(v, off, 64);
    __shared__ float sw_[2];
    if ((threadIdx.x & 63) == 0) sw_[threadIdx.x >> 6] = v;
    __syncthreads();
    if (threadIdx.x == 0) sumw2[0] = sw_[0] + sw_[1];
}

// ---------------------------------------------------------------------------
// Edge MLP with block-local compaction (R6 structure): block owns 32 atoms
// (2048 edges). Phase A compacts unmasked local ids into LDS, zeroes masked
// gr8 slots, and stores the per-64-edge unmask BITMAP (free from ballot).
// Phase B runs the dense exp-tanh d-loop over the ~1024 list.
// ---------------------------------------------------------------------------
__global__ __launch_bounds__(256) void edge_local(
    const float* __restrict__ x, const int* __restrict__ mask,
    const int* __restrict__ batch,
    const float4* __restrict__ pw4, const float4* __restrict__ gw4,
    const float* __restrict__ sumw2p,
    uint2* __restrict__ gr8, ull* __restrict__ bm, float* __restrict__ part)
{
    __shared__ unsigned short list[EDGES_PB];
    __shared__ int   lcnt;
    __shared__ float sp[N_STRUCT];
    __shared__ int   sbatch[ATOMS_PB];

    const int tid = threadIdx.x, lane = tid & 63;
    const int ebase = blockIdx.x * EDGES_PB;

    if (tid == 0) lcnt = 0;
    if (tid < N_STRUCT) sp[tid] = 0.f;
    if (tid < ATOMS_PB) sbatch[tid] = batch[blockIdx.x * ATOMS_PB + tid];
    __syncthreads();

    #pragma unroll
    for (int p = 0; p < EDGES_PB / 256; ++p) {           // 8 passes, coalesced
        int le = p * 256 + tid;
        int m = mask[ebase + le];
        unsigned long long bal = __ballot(m == 0);
        int wcnt = __popcll(bal);
        int pre  = __popcll(bal & ((1ull << lane) - 1ull));
        int wbase;
        if (lane == 0) {
            wbase = atomicAdd(&lcnt, wcnt);              // block-local ticket
            bm[(ebase + le) >> 6] = bal;                 // unmask bitmap word
        }
        wbase = __shfl(wbase, 0, 64);
        if (m == 0) list[wbase + pre] = (unsigned short)le;
        else        gr8[ebase + le] = make_uint2(0u, 0u);
    }
    __syncthreads();

    const int L = lcnt;
    const float sumw2 = sumw2p[0];

    for (int i = tid; i < L; i += 256) {
        int le  = list[i];
        int eid = ebase + le;
        const float* xp = x + (size_t)eid * 3;
        float x0 = xp[0], x1 = xp[1], x2 = xp[2];
        float rsum = 0.f, g0 = 0.f, g1 = 0.f, g2 = 0.f;
        for (int d = 0; d < HID; d += 4) {
            float4 wa = pw4[d], wb = pw4[d + 1], wc = pw4[d + 2], wd = pw4[d + 3];
            float4 Ga = gw4[d], Gb = gw4[d + 1], Gc = gw4[d + 2], Gd = gw4[d + 3];
            float ea = EXP2(fmaf(x0, wa.x, fmaf(x1, wa.y, x2 * wa.z)));
            float eb = EXP2(fmaf(x0, wb.x, fmaf(x1, wb.y, x2 * wb.z)));
            float ec = EXP2(fmaf(x0, wc.x, fmaf(x1, wc.y, x2 * wc.z)));
            float ed = EXP2(fmaf(x0, wd.x, fmaf(x1, wd.y, x2 * wd.z)));
            float aa = ea + 1.f, ab = eb + 1.f, ac = ec + 1.f, ad = ed + 1.f;
            float pab = aa * ab, pcd = ac * ad;
            float q   = __builtin_amdgcn_rcpf(pab * pcd);     // one rcp per 4 d
            float qab = q * pcd, qcd = q * pab;
            float ra = qab * ab, rb = qab * aa, rc = qcd * ad, rd = qcd * ac;
            rsum = fmaf(wa.w, ra, rsum);
            rsum = fmaf(wb.w, rb, rsum);
            rsum = fmaf(wc.w, rc, rsum);
            rsum = fmaf(wd.w, rd, rsum);
            float sa = fmaf(-ra, ra, ra);                     // r-r^2 = (1-t^2)/4
            float sb = fmaf(-rb, rb, rb);
            float sc = fmaf(-rc, rc, rc);
            float sd = fmaf(-rd, rd, rd);
            g0 = fmaf(sa, Ga.x, g0); g1 = fmaf(sa, Ga.y, g1); g2 = fmaf(sa, Ga.z, g2);
            g0 = fmaf(sb, Gb.x, g0); g1 = fmaf(sb, Gb.y, g1); g2 = fmaf(sb, Gb.z, g2);
            g0 = fmaf(sc, Gc.x, g0); g1 = fmaf(sc, Gc.y, g1); g2 = fmaf(sc, Gc.z, g2);
            g0 = fmaf(sd, Gd.x, g0); g1 = fmaf(sd, Gd.y, g1); g2 = fmaf(sd, Gd.z, g2);
        }
        float e = fmaf(-2.f, rsum, sumw2);
        uint lo = bf_rne(g0) | (bf_rne(g1) << 16);
        uint hi = bf_rne(g2);
        gr8[eid] = make_uint2(lo, hi);
        atomicAdd(&sp[sbatch[le >> 6]], e);
    }
    __syncthreads();
    if (tid < N_STRUCT) part[(size_t)tid * NBLK_EL + blockIdx.x] = sp[tid];
}

// ---------------------------------------------------------------------------
// Forces (R6 low-VGPR structure + bitmap gather filter): block owns 64 atoms;
// LDS-transposes its 64x64 nidx tile, then wave = 2 atoms/iter. Before each
// random gather, test the TARGET's unmask bit (800KB L2-resident bitmap) —
// masked targets hold zeros, so skipping them halves the 64B line misses.
// Blocks 0..31 also reduce preds partials.
// ---------------------------------------------------------------------------
__global__ __launch_bounds__(256) void atom_fused(
    const uint2* __restrict__ gr8, const int* __restrict__ nidx,
    const int* __restrict__ pos, const int* __restrict__ mask,
    const ull* __restrict__ bm, const float* __restrict__ part,
    float* __restrict__ out)
{
    __shared__ int tile[64][65];
    __shared__ float sv[4];
    const int tid = threadIdx.x, lane = tid & 63, w = tid >> 6;
    const int n0 = blockIdx.x * 64;

    #pragma unroll
    for (int i = 0; i < 16; ++i) {                 // coalesced read of nidx[K,N]
        int k = i * 4 + w, n = n0 + lane;
        tile[k][lane] = (n < N_ATOMS) ? nidx[k * N_ATOMS + n] : 0;
    }
    __syncthreads();

    #pragma unroll 2
    for (int j = 0; j < 8; ++j) {                  // wave: atoms nA, nA+1
        int nlA = w * 16 + 2 * j;
        int nA  = n0 + nlA;
        int nB  = nA + 1;
        bool vA = (nA < N_ATOMS), vB = (nB < N_ATOMS);

        float fA0 = 0.f, fA1 = 0.f, fA2 = 0.f, fB0 = 0.f, fB1 = 0.f, fB2 = 0.f;
        if (vA) {
            int eiA = nA * 64 + lane;
            int mA = mask[eiA];
            uint2 aA = gr8[eiA];                   // coalesced; masked slots are 0
            uint2 bA = make_uint2(0u, 0u);
            if (!mA) {
                int gA = tile[lane][nlA] * 64 + pos[eiA];
                if ((bm[gA >> 6] >> (gA & 63)) & 1ull)      // target unmasked?
                    bA = gr8[gA];                  // aligned 8B random gather
            }
            fA0 = ubf_lo(aA.x) - ubf_lo(bA.x);
            fA1 = ubf_hi(aA.x) - ubf_hi(bA.x);
            fA2 = ubf_lo(aA.y) - ubf_lo(bA.y);
        }
        if (vB) {
            int eiB = nB * 64 + lane;
            int mB = mask[eiB];
            uint2 aB = gr8[eiB];
            uint2 bB = make_uint2(0u, 0u);
            if (!mB) {
                int gB = tile[lane][nlA + 1] * 64 + pos[eiB];
                if ((bm[gB >> 6] >> (gB & 63)) & 1ull)
                    bB = gr8[gB];
            }
            fB0 = ubf_lo(aB.x) - ubf_lo(bB.x);
            fB1 = ubf_hi(aB.x) - ubf_hi(bB.x);
            fB2 = ubf_lo(aB.y) - ubf_lo(bB.y);
        }

        for (int off = 32; off; off >>= 1) {
            fA0 += __shfl_down(fA0, off, 64);
            fA1 += __shfl_down(fA1, off, 64);
            fA2 += __shfl_down(fA2, off, 64);
            fB0 += __shfl_down(fB0, off, 64);
            fB1 += __shfl_down(fB1, off, 64);
            fB2 += __shfl_down(fB2, off, 64);
        }
        if (lane == 0 && vA) {
            float* fo = out + N_STRUCT + (size_t)nA * 3;
            fo[0] = fA0; fo[1] = fA1; fo[2] = fA2;
            if (vB) { fo[3] = fB0; fo[4] = fB1; fo[5] = fB2; }
        }
    }

    if (blockIdx.x < N_STRUCT) {                   // fused preds reduction
        int s = blockIdx.x;
        float v = 0.f;
        for (int i = tid; i < NBLK_EL; i += 256) v += part[(size_t)s * NBLK_EL + i];
        for (int off = 32; off; off >>= 1) v += __shfl_down(v, off, 64);
        if (lane == 0) sv[w] = v;
        __syncthreads();
        if (tid == 0) out[s] = sv[0] + sv[1] + sv[2] + sv[3];
    }
}

// ---------------------------------------------------------------------------
extern "C" void kernel_launch(void* const* d_in, const int* in_sizes, int n_in,
                              void* d_out, int out_size, void* d_ws, size_t ws_size,
                              hipStream_t stream)
{
    const float* x    = (const float*)d_in[0];
    const int*   nidx = (const int*)d_in[1];   // [K, N]
    const int*   npos = (const int*)d_in[2];   // [N, K]
    const int*   mask = (const int*)d_in[3];   // [N, K]
    const int*   bidx = (const int*)d_in[4];   // [N]
    const float* W1   = (const float*)d_in[5]; // [3, HID]
    const float* w2   = (const float*)d_in[6]; // [HID]
    float* out = (float*)d_out;

    char* ws = (char*)d_ws;
    uint2* gr8  = (uint2*)ws;                                       // 51.2 MB
    ull*   bm   = (ull*)(ws + (size_t)N_EDGE * 8);                  // 800 KB
    float* part = (float*)(ws + (size_t)N_EDGE * 8 + (size_t)(N_EDGE / 64) * 8);
    char*  tail = ws + (size_t)N_EDGE * 8 + (size_t)(N_EDGE / 64) * 8
                     + (size_t)N_STRUCT * NBLK_EL * sizeof(float);
    float4* pw4   = (float4*)tail;                                  // 2 KB
    float4* gw4   = (float4*)(tail + HID * 16);                     // 2 KB
    float*  sumw2 = (float*)(tail + 2 * HID * 16);

    hipLaunchKernelGGL(prep_kernel, dim3(1), dim3(128), 0, stream,
                       W1, w2, pw4, gw4, sumw2);
    hipLaunchKernelGGL(edge_local, dim3(NBLK_EL), dim3(256), 0, stream,
                       x, mask, bidx, pw4, gw4, sumw2, gr8, bm, part);
    hipLaunchKernelGGL(atom_fused, dim3(NBLK_A), dim3(256), 0, stream,
                       gr8, nidx, npos, mask, bm, part, out);
}